// Round 12
// baseline (482.705 us; speedup 1.0000x reference)
//
#include <hip/hip_runtime.h>
#include <math.h>

#define N_NODES 100000
#define N_EDGES 1600000
#define N_GRAPHS 64
#define HID 64
#define LN_EPS 1e-5f
#define NBK ((N_NODES + 511) / 512)       // 196 scan blocks (512 thr each)
#define KD_BLOCKS 2048
#define KD_WAVES (KD_BLOCKS * 4)          // 8192 waves, one node-chunk per wave
#define KD_CHUNK ((N_NODES + KD_WAVES - 1) / KD_WAVES)  // 13 contiguous nodes/wave

__device__ __forceinline__ float waveReduceSum(float v) {
#pragma unroll
    for (int off = 32; off > 0; off >>= 1)
        v += __shfl_xor(v, off, 64);
    return v;
}

__device__ __forceinline__ float groupReduceSum16(float v) {
#pragma unroll
    for (int off = 8; off > 0; off >>= 1)
        v += __shfl_xor(v, off, 64);
    return v;
}

__device__ __forceinline__ unsigned rne_bf16(float f) {
    unsigned u = __float_as_uint(f);
    return (u + 0x7fffu + ((u >> 16) & 1u)) >> 16;
}

// K0: per-node transforms (xl, xr both packed bf16) + all workspace init.
__global__ __launch_bounds__(256) void k0_transform(
    const float* __restrict__ x,
    const float* __restrict__ Wl, const float* __restrict__ bl,
    const float* __restrict__ Wr, const float* __restrict__ br,
    uint2* __restrict__ xlh, uint2* __restrict__ xrh,
    int* __restrict__ deg,
    float* __restrict__ gsum, float* __restrict__ gcnt,
    double* __restrict__ stats, int* __restrict__ ctrs) {
    if (blockIdx.x == 0) {
        for (int i = threadIdx.x; i < N_GRAPHS * HID; i += blockDim.x) gsum[i] = 0.f;
        if (threadIdx.x < N_GRAPHS) gcnt[threadIdx.x] = 0.f;
        if (threadIdx.x < 2) stats[threadIdx.x] = 0.0;
        if (threadIdx.x < 2) ctrs[threadIdx.x] = 0;
    }
    int t = blockIdx.x * blockDim.x + threadIdx.x;
    int n = t >> 4;
    int cg = t & 15;
    if (n >= N_NODES) return;
    float4 xv = ((const float4*)x)[n];
    float4 w0 = ((const float4*)Wl)[0 * 16 + cg];
    float4 w1 = ((const float4*)Wl)[1 * 16 + cg];
    float4 w2 = ((const float4*)Wl)[2 * 16 + cg];
    float4 w3 = ((const float4*)Wl)[3 * 16 + cg];
    float4 bv = ((const float4*)bl)[cg];
    float4 vl;
    vl.x = bv.x + xv.x * w0.x + xv.y * w1.x + xv.z * w2.x + xv.w * w3.x;
    vl.y = bv.y + xv.x * w0.y + xv.y * w1.y + xv.z * w2.y + xv.w * w3.y;
    vl.z = bv.z + xv.x * w0.z + xv.y * w1.z + xv.z * w2.z + xv.w * w3.z;
    vl.w = bv.w + xv.x * w0.w + xv.y * w1.w + xv.z * w2.w + xv.w * w3.w;
    w0 = ((const float4*)Wr)[0 * 16 + cg];
    w1 = ((const float4*)Wr)[1 * 16 + cg];
    w2 = ((const float4*)Wr)[2 * 16 + cg];
    w3 = ((const float4*)Wr)[3 * 16 + cg];
    bv = ((const float4*)br)[cg];
    float4 vr;
    vr.x = bv.x + xv.x * w0.x + xv.y * w1.x + xv.z * w2.x + xv.w * w3.x;
    vr.y = bv.y + xv.x * w0.y + xv.y * w1.y + xv.z * w2.y + xv.w * w3.y;
    vr.z = bv.z + xv.x * w0.z + xv.y * w1.z + xv.z * w2.z + xv.w * w3.z;
    vr.w = bv.w + xv.x * w0.w + xv.y * w1.w + xv.z * w2.w + xv.w * w3.w;
    uint2 p;
    p.x = rne_bf16(vl.x) | (rne_bf16(vl.y) << 16);
    p.y = rne_bf16(vl.z) | (rne_bf16(vl.w) << 16);
    xlh[n * 16 + cg] = p;
    uint2 r;
    r.x = rne_bf16(vr.x) | (rne_bf16(vr.y) << 16);
    r.y = rne_bf16(vr.z) | (rne_bf16(vr.w) << 16);
    xrh[n * 16 + cg] = r;
    if (cg == 0) deg[n] = 0;
}

// KA: degree histogram + per-edge rank capture (coalesced int4 rank writes).
__global__ __launch_bounds__(256) void ka_rank(const int* __restrict__ ei,
                                               int* __restrict__ deg,
                                               int* __restrict__ erank) {
    int q = blockIdx.x * blockDim.x + threadIdx.x;
    if (q >= N_EDGES / 4) return;
    int4 d4 = ((const int4*)(ei + N_EDGES))[q];
    int4 r4;
    r4.x = atomicAdd(&deg[d4.x], 1);
    r4.y = atomicAdd(&deg[d4.y], 1);
    r4.z = atomicAdd(&deg[d4.z], 1);
    r4.w = atomicAdd(&deg[d4.w], 1);
    ((int4*)erank)[q] = r4;
}

// KB: fused two-level exclusive scan (one launch). 196 blocks x 512 thr:
// block-local scan of deg -> rowptr + bsum[b]; last-done block rescans bsum.
__global__ __launch_bounds__(512) void kb_scan(const int* __restrict__ deg,
                                               int* __restrict__ rowptr,
                                               int* __restrict__ bsum,
                                               int* __restrict__ kctr) {
    __shared__ int s[512];
    __shared__ int sLast;
    int i = blockIdx.x * 512 + threadIdx.x;
    int v = (i < N_NODES) ? deg[i] : 0;
    s[threadIdx.x] = v;
    __syncthreads();
#pragma unroll
    for (int off = 1; off < 512; off <<= 1) {
        int t = (threadIdx.x >= off) ? s[threadIdx.x - off] : 0;
        __syncthreads();
        s[threadIdx.x] += t;
        __syncthreads();
    }
    if (i < N_NODES) rowptr[i] = s[threadIdx.x] - v;  // block-local exclusive
    if (threadIdx.x == 511) bsum[blockIdx.x] = s[511];
    __threadfence();
    __syncthreads();
    if (threadIdx.x == 0) sLast = (atomicAdd(kctr, 1) == gridDim.x - 1);
    __syncthreads();
    if (sLast) {
        __threadfence();
        int b = (threadIdx.x < NBK) ? bsum[threadIdx.x] : 0;
        s[threadIdx.x] = b;
        __syncthreads();
#pragma unroll
        for (int off = 1; off < 512; off <<= 1) {
            int t = (threadIdx.x >= off) ? s[threadIdx.x - off] : 0;
            __syncthreads();
            s[threadIdx.x] += t;
            __syncthreads();
        }
        if (threadIdx.x < NBK) bsum[threadIdx.x] = s[threadIdx.x] - b;
    }
}

// KC: atomic-free rank-based placement, XCD-partitioned by dst (write-merge).
__global__ __launch_bounds__(256) void kc_place(const int* __restrict__ ei,
                                                const int* __restrict__ rowptr,
                                                const int* __restrict__ bsum,
                                                const int* __restrict__ erank,
                                                int* __restrict__ esrc) {
    int xcd = blockIdx.x & 7;
    int sub = blockIdx.x >> 3;                 // 0..63
    int lo = xcd * (N_NODES / 8);
    int hi = lo + (N_NODES / 8);
    int tid = sub * 256 + (int)threadIdx.x;
    for (int q = tid; q < N_EDGES / 4; q += 64 * 256) {
        int4 d4 = ((const int4*)(ei + N_EDGES))[q];
        int i0 = q * 4;
        if (d4.x >= lo && d4.x < hi)
            esrc[rowptr[d4.x] + bsum[d4.x >> 9] + erank[i0 + 0]] = ei[i0 + 0];
        if (d4.y >= lo && d4.y < hi)
            esrc[rowptr[d4.y] + bsum[d4.y >> 9] + erank[i0 + 1]] = ei[i0 + 1];
        if (d4.z >= lo && d4.z < hi)
            esrc[rowptr[d4.z] + bsum[d4.z >> 9] + erank[i0 + 2]] = ei[i0 + 2];
        if (d4.w >= lo && d4.w < hi)
            esrc[rowptr[d4.w] + bsum[d4.w >> 9] + erank[i0 + 3]] = ei[i0 + 3];
    }
}

// KD: fused node aggregation + LN stats + graph pooling + (last block) head.
// Proven 4-slot x 16-lane uint2 body (VGPR 32, no spill); single full-range
// launch (2048 blocks = 100% CU fill; R11's half-split cost 46% occupancy).
// WRITE_SIZE >> 8MB is the spill sentinel (R7/R9 lesson).
__global__ __launch_bounds__(256, 8) void kd_node_agg(
    const int* __restrict__ rowptr, const int* __restrict__ bsum,
    const int* __restrict__ esrc,
    const uint2* __restrict__ xlh, const uint2* __restrict__ xrh,
    const float* __restrict__ att, const float* __restrict__ cb,
    const int* __restrict__ batch,
    float* __restrict__ gsum, float* __restrict__ gcnt,
    double* __restrict__ stats, int* __restrict__ ctr,
    const float* __restrict__ lnw, const float* __restrict__ lnb,
    const float* __restrict__ linw, const float* __restrict__ linb,
    float* __restrict__ y) {
    __shared__ float sS[4], sQ[4];
    __shared__ int sLast;
    int w = threadIdx.x >> 6;             // wave-in-block 0..3
    int lane = threadIdx.x & 63;
    int slot = lane >> 4;                 // 0..3: edge slot
    int cg = lane & 15;                   // channel group (4 ch)
    int wid = blockIdx.x * 4 + w;
    int n0 = wid * KD_CHUNK;
    int n1 = min(n0 + KD_CHUNK, N_NODES);

    float4 av = ((const float4*)att)[cg];
    float4 cv = ((const float4*)cb)[cg];

    float lsum = 0.f, lsq = 0.f;
    float gacc0 = 0.f, gacc1 = 0.f, gacc2 = 0.f, gacc3 = 0.f;
    float runcnt = 0.f;
    int cur_g = -1;

    for (int n = n0; n < n1; ++n) {
        int beg = rowptr[n] + bsum[n >> 9];
        int end = (n + 1 < N_NODES) ? (rowptr[n + 1] + bsum[(n + 1) >> 9]) : N_EDGES;
        uint2 rp = xrh[n * 16 + cg];
        float4 xr;
        xr.x = __uint_as_float(rp.x << 16);
        xr.y = __uint_as_float(rp.x & 0xffff0000u);
        xr.z = __uint_as_float(rp.y << 16);
        xr.w = __uint_as_float(rp.y & 0xffff0000u);
        float num0 = 0.f, num1 = 0.f, num2 = 0.f, num3 = 0.f, den = 0.f;
        int j = beg + slot;
        uint2 p = make_uint2(0, 0);
        if (j < end) p = xlh[esrc[j] * 16 + cg];
        for (int j0 = beg; j0 < end; j0 += 4) {
            uint2 pc = p;
            bool vc = (j0 + slot) < end;
            int jn = j0 + 4 + slot;
            if (jn < end) p = xlh[esrc[jn] * 16 + cg];
            float f0 = __uint_as_float(pc.x << 16);
            float f1 = __uint_as_float(pc.x & 0xffff0000u);
            float f2 = __uint_as_float(pc.y << 16);
            float f3 = __uint_as_float(pc.y & 0xffff0000u);
            float h0 = f0 + xr.x, h1 = f1 + xr.y, h2 = f2 + xr.z, h3 = f3 + xr.w;
            float l0 = fmaxf(h0, 0.f) + 0.2f * fminf(h0, 0.f);
            float l1 = fmaxf(h1, 0.f) + 0.2f * fminf(h1, 0.f);
            float l2 = fmaxf(h2, 0.f) + 0.2f * fminf(h2, 0.f);
            float l3 = fmaxf(h3, 0.f) + 0.2f * fminf(h3, 0.f);
            float part = l0 * av.x + l1 * av.y + l2 * av.z + l3 * av.w;
            float e = groupReduceSum16(part);   // within-slot 16-lane reduce
            float ex = vc ? __expf(e) : 0.f;
            den += ex;
            num0 += ex * f0; num1 += ex * f1; num2 += ex * f2; num3 += ex * f3;
        }
#pragma unroll
        for (int off = 16; off <= 32; off <<= 1) {
            num0 += __shfl_xor(num0, off, 64);
            num1 += __shfl_xor(num1, off, 64);
            num2 += __shfl_xor(num2, off, 64);
            num3 += __shfl_xor(num3, off, 64);
            den += __shfl_xor(den, off, 64);
        }
        float inv = (den > 0.f) ? (1.f / den) : 0.f;
        float v0 = fmaxf(num0 * inv + cv.x, 0.f);
        float v1 = fmaxf(num1 * inv + cv.y, 0.f);
        float v2 = fmaxf(num2 * inv + cv.z, 0.f);
        float v3 = fmaxf(num3 * inv + cv.w, 0.f);
        if (slot == 0) {   // values replicated across slots; count once
            lsum += v0 + v1 + v2 + v3;
            lsq += v0 * v0 + v1 * v1 + v2 * v2 + v3 * v3;
            int g = batch[n];
            if (g != cur_g) {
                if (cur_g >= 0) {
                    unsafeAtomicAdd(&gsum[cur_g * HID + cg * 4 + 0], gacc0);
                    unsafeAtomicAdd(&gsum[cur_g * HID + cg * 4 + 1], gacc1);
                    unsafeAtomicAdd(&gsum[cur_g * HID + cg * 4 + 2], gacc2);
                    unsafeAtomicAdd(&gsum[cur_g * HID + cg * 4 + 3], gacc3);
                    if (cg == 0) unsafeAtomicAdd(&gcnt[cur_g], runcnt);
                }
                cur_g = g;
                gacc0 = gacc1 = gacc2 = gacc3 = 0.f;
                runcnt = 0.f;
            }
            gacc0 += v0; gacc1 += v1; gacc2 += v2; gacc3 += v3;
            runcnt += 1.f;
        }
    }
    if (cur_g >= 0) {   // only slot-0 lanes have cur_g >= 0
        unsafeAtomicAdd(&gsum[cur_g * HID + cg * 4 + 0], gacc0);
        unsafeAtomicAdd(&gsum[cur_g * HID + cg * 4 + 1], gacc1);
        unsafeAtomicAdd(&gsum[cur_g * HID + cg * 4 + 2], gacc2);
        unsafeAtomicAdd(&gsum[cur_g * HID + cg * 4 + 3], gacc3);
        if (cg == 0) unsafeAtomicAdd(&gcnt[cur_g], runcnt);
    }
    lsum = groupReduceSum16(lsum);
    lsq = groupReduceSum16(lsq);
    if (lane == 0) { sS[w] = lsum; sQ[w] = lsq; }
    __syncthreads();
    if (threadIdx.x == 0) {
        double ds = 0.0, dq = 0.0;
#pragma unroll
        for (int i = 0; i < 4; ++i) { ds += (double)sS[i]; dq += (double)sQ[i]; }
        unsafeAtomicAdd(&stats[0], ds);
        unsafeAtomicAdd(&stats[1], dq);
    }
    // last-block-done: final block computes the per-graph head (fused k4).
    __threadfence();
    __syncthreads();
    if (threadIdx.x == 0) sLast = (atomicAdd(ctr, 1) == KD_BLOCKS - 1);
    __syncthreads();
    if (sLast) {
        __threadfence();
        double tot = (double)N_NODES * (double)HID;
        double mu = stats[0] / tot;
        double var = stats[1] / tot - mu * mu;
        float rs = rsqrtf((float)var + LN_EPS);
        float fmu = (float)mu;
        int l64 = threadIdx.x & 63;
        int wv = threadIdx.x >> 6;
        for (int g = wv * 16; g < wv * 16 + 16; ++g) {
            float cnt = fmaxf(gcnt[g], 1.f);
            float pooled =
                (gsum[g * HID + l64] / cnt - fmu) * rs * lnw[l64] + lnb[l64];
            float t = waveReduceSum(pooled * linw[l64]);
            if (l64 == 0) y[g] = 1.f / (1.f + __expf(-(t + linb[0])));
        }
    }
}

extern "C" void kernel_launch(void* const* d_in, const int* in_sizes, int n_in,
                              void* d_out, int out_size, void* d_ws, size_t ws_size,
                              hipStream_t stream) {
    const float* x = (const float*)d_in[0];
    const int* ei = (const int*)d_in[1];
    const int* batch = (const int*)d_in[2];
    const float* Wl = (const float*)d_in[3];
    const float* bl = (const float*)d_in[4];
    const float* Wr = (const float*)d_in[5];
    const float* br = (const float*)d_in[6];
    const float* att = (const float*)d_in[7];
    const float* cb = (const float*)d_in[8];
    const float* lnw = (const float*)d_in[9];
    const float* lnb = (const float*)d_in[10];
    const float* linw = (const float*)d_in[11];
    const float* linb = (const float*)d_in[12];
    float* y = (float*)d_out;

    char* ws = (char*)d_ws;
    uint2* xlh = (uint2*)ws;                                     // N*16 uint2
    uint2* xrh = (uint2*)(ws + (size_t)N_NODES * 128);           // N*16 uint2
    float* gsum = (float*)(ws + (size_t)N_NODES * 256);          // 64*64
    float* gcnt = gsum + N_GRAPHS * HID;                         // 64
    double* stats = (double*)(gcnt + N_GRAPHS);                  // 2 doubles
    int* ctrs = (int*)(stats + 2);                               // [kd ctr, kb ctr]
    int* rowptr = ctrs + 2;                                      // N+1
    int* deg = rowptr + (N_NODES + 1);                           // N
    int* bsum = deg + N_NODES;                                   // 512 (196 used)
    int* erank = bsum + 512;                                     // E
    int* esrc = erank + N_EDGES;                                 // E

    k0_transform<<<(N_NODES * 16 + 255) / 256, 256, 0, stream>>>(
        x, Wl, bl, Wr, br, xlh, xrh, deg, gsum, gcnt, stats, ctrs);
    ka_rank<<<(N_EDGES / 4 + 255) / 256, 256, 0, stream>>>(ei, deg, erank);
    kb_scan<<<NBK, 512, 0, stream>>>(deg, rowptr, bsum, ctrs + 1);
    kc_place<<<512, 256, 0, stream>>>(ei, rowptr, bsum, erank, esrc);
    kd_node_agg<<<KD_BLOCKS, 256, 0, stream>>>(
        rowptr, bsum, esrc, xlh, xrh, att, cb, batch, gsum, gcnt, stats,
        ctrs, lnw, lnb, linw, linb, y);
}

// Round 13
// 372.086 us; speedup vs baseline: 1.2973x; 1.2973x over previous
//
#include <hip/hip_runtime.h>
#include <math.h>

#define N_NODES 100000
#define N_EDGES 1600000
#define N_GRAPHS 64
#define HID 64
#define LN_EPS 1e-5f
#define NB_SCAN ((N_NODES + 255) / 256)   // 391 scan blocks
#define KD_BLOCKS 4096
#define KD_WAVES (KD_BLOCKS * 4)          // 16384 waves: 2 scheduling rounds
#define KD_CHUNK ((N_NODES + KD_WAVES - 1) / KD_WAVES)  // 7 contiguous nodes/wave

__device__ __forceinline__ float waveReduceSum(float v) {
#pragma unroll
    for (int off = 32; off > 0; off >>= 1)
        v += __shfl_xor(v, off, 64);
    return v;
}

__device__ __forceinline__ float groupReduceSum16(float v) {
#pragma unroll
    for (int off = 8; off > 0; off >>= 1)
        v += __shfl_xor(v, off, 64);
    return v;
}

__device__ __forceinline__ unsigned rne_bf16(float f) {
    unsigned u = __float_as_uint(f);
    return (u + 0x7fffu + ((u >> 16) & 1u)) >> 16;
}

// K0: per-node transforms (xl, xr both packed bf16) + all workspace init.
// NOTE (R12 lesson): no __threadfence/last-block fusion anywhere — device
// fences cost ~65ns×blocks in L2 writeback on non-coherent XCDs.
__global__ __launch_bounds__(256) void k0_transform(
    const float* __restrict__ x,
    const float* __restrict__ Wl, const float* __restrict__ bl,
    const float* __restrict__ Wr, const float* __restrict__ br,
    uint2* __restrict__ xlh, uint2* __restrict__ xrh,
    int* __restrict__ deg,
    float* __restrict__ gsum, float* __restrict__ gcnt,
    double* __restrict__ stats) {
    if (blockIdx.x == 0) {
        for (int i = threadIdx.x; i < N_GRAPHS * HID; i += blockDim.x) gsum[i] = 0.f;
        if (threadIdx.x < N_GRAPHS) gcnt[threadIdx.x] = 0.f;
        if (threadIdx.x < 2) stats[threadIdx.x] = 0.0;
    }
    int t = blockIdx.x * blockDim.x + threadIdx.x;
    int n = t >> 4;
    int cg = t & 15;
    if (n >= N_NODES) return;
    float4 xv = ((const float4*)x)[n];
    float4 w0 = ((const float4*)Wl)[0 * 16 + cg];
    float4 w1 = ((const float4*)Wl)[1 * 16 + cg];
    float4 w2 = ((const float4*)Wl)[2 * 16 + cg];
    float4 w3 = ((const float4*)Wl)[3 * 16 + cg];
    float4 bv = ((const float4*)bl)[cg];
    float4 vl;
    vl.x = bv.x + xv.x * w0.x + xv.y * w1.x + xv.z * w2.x + xv.w * w3.x;
    vl.y = bv.y + xv.x * w0.y + xv.y * w1.y + xv.z * w2.y + xv.w * w3.y;
    vl.z = bv.z + xv.x * w0.z + xv.y * w1.z + xv.z * w2.z + xv.w * w3.z;
    vl.w = bv.w + xv.x * w0.w + xv.y * w1.w + xv.z * w2.w + xv.w * w3.w;
    w0 = ((const float4*)Wr)[0 * 16 + cg];
    w1 = ((const float4*)Wr)[1 * 16 + cg];
    w2 = ((const float4*)Wr)[2 * 16 + cg];
    w3 = ((const float4*)Wr)[3 * 16 + cg];
    bv = ((const float4*)br)[cg];
    float4 vr;
    vr.x = bv.x + xv.x * w0.x + xv.y * w1.x + xv.z * w2.x + xv.w * w3.x;
    vr.y = bv.y + xv.x * w0.y + xv.y * w1.y + xv.z * w2.y + xv.w * w3.y;
    vr.z = bv.z + xv.x * w0.z + xv.y * w1.z + xv.z * w2.z + xv.w * w3.z;
    vr.w = bv.w + xv.x * w0.w + xv.y * w1.w + xv.z * w2.w + xv.w * w3.w;
    uint2 p;
    p.x = rne_bf16(vl.x) | (rne_bf16(vl.y) << 16);
    p.y = rne_bf16(vl.z) | (rne_bf16(vl.w) << 16);
    xlh[n * 16 + cg] = p;
    uint2 r;
    r.x = rne_bf16(vr.x) | (rne_bf16(vr.y) << 16);
    r.y = rne_bf16(vr.z) | (rne_bf16(vr.w) << 16);
    xrh[n * 16 + cg] = r;
    if (cg == 0) deg[n] = 0;
}

// KA: degree histogram + per-edge rank capture (coalesced int4 rank writes).
__global__ __launch_bounds__(256) void ka_rank(const int* __restrict__ ei,
                                               int* __restrict__ deg,
                                               int* __restrict__ erank) {
    int q = blockIdx.x * blockDim.x + threadIdx.x;
    if (q >= N_EDGES / 4) return;
    int4 d4 = ((const int4*)(ei + N_EDGES))[q];
    int4 r4;
    r4.x = atomicAdd(&deg[d4.x], 1);
    r4.y = atomicAdd(&deg[d4.y], 1);
    r4.z = atomicAdd(&deg[d4.z], 1);
    r4.w = atomicAdd(&deg[d4.w], 1);
    ((int4*)erank)[q] = r4;
}

// KB1: per-block exclusive scan of deg -> rowptr (block-local) + block totals.
__global__ __launch_bounds__(256) void kb1_scan(const int* __restrict__ deg,
                                                int* __restrict__ rowptr,
                                                int* __restrict__ bsum) {
    __shared__ int s[256];
    int i = blockIdx.x * 256 + threadIdx.x;
    int v = (i < N_NODES) ? deg[i] : 0;
    s[threadIdx.x] = v;
    __syncthreads();
#pragma unroll
    for (int off = 1; off < 256; off <<= 1) {
        int t = (threadIdx.x >= off) ? s[threadIdx.x - off] : 0;
        __syncthreads();
        s[threadIdx.x] += t;
        __syncthreads();
    }
    if (i < N_NODES) rowptr[i] = s[threadIdx.x] - v;  // block-local exclusive
    if (threadIdx.x == 255) bsum[blockIdx.x] = s[255];
}

// KB2: single-block exclusive scan of block totals (NB_SCAN=391 <= 512).
// Consumers (kc, kd) add bsum[x>>8] on the fly.
__global__ __launch_bounds__(512) void kb2_scan(int* __restrict__ bsum) {
    __shared__ int s[512];
    int v = (threadIdx.x < NB_SCAN) ? bsum[threadIdx.x] : 0;
    s[threadIdx.x] = v;
    __syncthreads();
#pragma unroll
    for (int off = 1; off < 512; off <<= 1) {
        int t = (threadIdx.x >= off) ? s[threadIdx.x - off] : 0;
        __syncthreads();
        s[threadIdx.x] += t;
        __syncthreads();
    }
    if (threadIdx.x < NB_SCAN) bsum[threadIdx.x] = s[threadIdx.x] - v;
}

// KC: atomic-free rank-based placement, XCD-partitioned by dst (write-merge).
__global__ __launch_bounds__(256) void kc_place(const int* __restrict__ ei,
                                                const int* __restrict__ rowptr,
                                                const int* __restrict__ bsum,
                                                const int* __restrict__ erank,
                                                int* __restrict__ esrc) {
    int xcd = blockIdx.x & 7;
    int sub = blockIdx.x >> 3;                 // 0..63
    int lo = xcd * (N_NODES / 8);
    int hi = lo + (N_NODES / 8);
    int tid = sub * 256 + (int)threadIdx.x;
    for (int q = tid; q < N_EDGES / 4; q += 64 * 256) {
        int4 d4 = ((const int4*)(ei + N_EDGES))[q];
        int i0 = q * 4;
        if (d4.x >= lo && d4.x < hi)
            esrc[rowptr[d4.x] + bsum[d4.x >> 8] + erank[i0 + 0]] = ei[i0 + 0];
        if (d4.y >= lo && d4.y < hi)
            esrc[rowptr[d4.y] + bsum[d4.y >> 8] + erank[i0 + 1]] = ei[i0 + 1];
        if (d4.z >= lo && d4.z < hi)
            esrc[rowptr[d4.z] + bsum[d4.z >> 8] + erank[i0 + 2]] = ei[i0 + 2];
        if (d4.w >= lo && d4.w < hi)
            esrc[rowptr[d4.w] + bsum[d4.w >> 8] + erank[i0 + 3]] = ei[i0 + 3];
    }
}

// KD: fused node aggregation + LN stats + graph pooling. Proven R8/R10 body
// (4 slots x 16 lanes, uint2, VGPR 32). bf16 xr (proven FETCH cut). 4096
// blocks = 2 scheduling rounds for wave-drain backfill (R10 showed 40% idle
// tail with a one-round grid). No fences, no widened registers (R7/R9/R12).
__global__ __launch_bounds__(256, 8) void kd_node_agg(
    const int* __restrict__ rowptr, const int* __restrict__ bsum,
    const int* __restrict__ esrc,
    const uint2* __restrict__ xlh, const uint2* __restrict__ xrh,
    const float* __restrict__ att, const float* __restrict__ cb,
    const int* __restrict__ batch,
    float* __restrict__ gsum, float* __restrict__ gcnt,
    double* __restrict__ stats) {
    __shared__ float sS[4], sQ[4];
    int w = threadIdx.x >> 6;             // wave-in-block 0..3
    int lane = threadIdx.x & 63;
    int slot = lane >> 4;                 // 0..3: edge slot
    int cg = lane & 15;                   // channel group (4 ch)
    int wid = blockIdx.x * 4 + w;
    int n0 = wid * KD_CHUNK;
    int n1 = min(n0 + KD_CHUNK, N_NODES);

    float4 av = ((const float4*)att)[cg];
    float4 cv = ((const float4*)cb)[cg];

    float lsum = 0.f, lsq = 0.f;
    float gacc0 = 0.f, gacc1 = 0.f, gacc2 = 0.f, gacc3 = 0.f;
    float runcnt = 0.f;
    int cur_g = -1;

    for (int n = n0; n < n1; ++n) {
        int beg = rowptr[n] + bsum[n >> 8];
        int end = (n + 1 < N_NODES) ? (rowptr[n + 1] + bsum[(n + 1) >> 8]) : N_EDGES;
        uint2 rp = xrh[n * 16 + cg];
        float4 xr;
        xr.x = __uint_as_float(rp.x << 16);
        xr.y = __uint_as_float(rp.x & 0xffff0000u);
        xr.z = __uint_as_float(rp.y << 16);
        xr.w = __uint_as_float(rp.y & 0xffff0000u);
        float num0 = 0.f, num1 = 0.f, num2 = 0.f, num3 = 0.f, den = 0.f;
        int j = beg + slot;
        uint2 p = make_uint2(0, 0);
        if (j < end) p = xlh[esrc[j] * 16 + cg];
        for (int j0 = beg; j0 < end; j0 += 4) {
            uint2 pc = p;
            bool vc = (j0 + slot) < end;
            int jn = j0 + 4 + slot;
            if (jn < end) p = xlh[esrc[jn] * 16 + cg];
            float f0 = __uint_as_float(pc.x << 16);
            float f1 = __uint_as_float(pc.x & 0xffff0000u);
            float f2 = __uint_as_float(pc.y << 16);
            float f3 = __uint_as_float(pc.y & 0xffff0000u);
            float h0 = f0 + xr.x, h1 = f1 + xr.y, h2 = f2 + xr.z, h3 = f3 + xr.w;
            float l0 = fmaxf(h0, 0.f) + 0.2f * fminf(h0, 0.f);
            float l1 = fmaxf(h1, 0.f) + 0.2f * fminf(h1, 0.f);
            float l2 = fmaxf(h2, 0.f) + 0.2f * fminf(h2, 0.f);
            float l3 = fmaxf(h3, 0.f) + 0.2f * fminf(h3, 0.f);
            float part = l0 * av.x + l1 * av.y + l2 * av.z + l3 * av.w;
            float e = groupReduceSum16(part);   // within-slot 16-lane reduce
            float ex = vc ? __expf(e) : 0.f;
            den += ex;
            num0 += ex * f0; num1 += ex * f1; num2 += ex * f2; num3 += ex * f3;
        }
#pragma unroll
        for (int off = 16; off <= 32; off <<= 1) {
            num0 += __shfl_xor(num0, off, 64);
            num1 += __shfl_xor(num1, off, 64);
            num2 += __shfl_xor(num2, off, 64);
            num3 += __shfl_xor(num3, off, 64);
            den += __shfl_xor(den, off, 64);
        }
        float inv = (den > 0.f) ? (1.f / den) : 0.f;
        float v0 = fmaxf(num0 * inv + cv.x, 0.f);
        float v1 = fmaxf(num1 * inv + cv.y, 0.f);
        float v2 = fmaxf(num2 * inv + cv.z, 0.f);
        float v3 = fmaxf(num3 * inv + cv.w, 0.f);
        if (slot == 0) {   // values replicated across slots; count once
            lsum += v0 + v1 + v2 + v3;
            lsq += v0 * v0 + v1 * v1 + v2 * v2 + v3 * v3;
            int g = batch[n];
            if (g != cur_g) {
                if (cur_g >= 0) {
                    unsafeAtomicAdd(&gsum[cur_g * HID + cg * 4 + 0], gacc0);
                    unsafeAtomicAdd(&gsum[cur_g * HID + cg * 4 + 1], gacc1);
                    unsafeAtomicAdd(&gsum[cur_g * HID + cg * 4 + 2], gacc2);
                    unsafeAtomicAdd(&gsum[cur_g * HID + cg * 4 + 3], gacc3);
                    if (cg == 0) unsafeAtomicAdd(&gcnt[cur_g], runcnt);
                }
                cur_g = g;
                gacc0 = gacc1 = gacc2 = gacc3 = 0.f;
                runcnt = 0.f;
            }
            gacc0 += v0; gacc1 += v1; gacc2 += v2; gacc3 += v3;
            runcnt += 1.f;
        }
    }
    if (cur_g >= 0) {   // only slot-0 lanes have cur_g >= 0
        unsafeAtomicAdd(&gsum[cur_g * HID + cg * 4 + 0], gacc0);
        unsafeAtomicAdd(&gsum[cur_g * HID + cg * 4 + 1], gacc1);
        unsafeAtomicAdd(&gsum[cur_g * HID + cg * 4 + 2], gacc2);
        unsafeAtomicAdd(&gsum[cur_g * HID + cg * 4 + 3], gacc3);
        if (cg == 0) unsafeAtomicAdd(&gcnt[cur_g], runcnt);
    }
    lsum = groupReduceSum16(lsum);
    lsq = groupReduceSum16(lsq);
    if (lane == 0) { sS[w] = lsum; sQ[w] = lsq; }
    __syncthreads();
    if (threadIdx.x == 0) {
        double ds = 0.0, dq = 0.0;
#pragma unroll
        for (int i = 0; i < 4; ++i) { ds += (double)sS[i]; dq += (double)sQ[i]; }
        unsafeAtomicAdd(&stats[0], ds);
        unsafeAtomicAdd(&stats[1], dq);
    }
}

// K4: per-graph head (separate launch; fusing it cost 135us in fences, R12).
__global__ __launch_bounds__(64) void k4_head(
    const float* __restrict__ gsum, const float* __restrict__ gcnt,
    const double* __restrict__ stats,
    const float* __restrict__ lnw, const float* __restrict__ lnb,
    const float* __restrict__ linw, const float* __restrict__ linb,
    float* __restrict__ y) {
    int g = blockIdx.x;
    int lane = threadIdx.x;
    double tot = (double)N_NODES * (double)HID;
    double mu = stats[0] / tot;
    double var = stats[1] / tot - mu * mu;
    float rs = rsqrtf((float)var + LN_EPS);
    float cnt = fmaxf(gcnt[g], 1.f);
    float pooled = (gsum[g * HID + lane] / cnt - (float)mu) * rs * lnw[lane] + lnb[lane];
    float t = waveReduceSum(pooled * linw[lane]);
    if (lane == 0) {
        float z = t + linb[0];
        y[g] = 1.f / (1.f + __expf(-z));
    }
}

extern "C" void kernel_launch(void* const* d_in, const int* in_sizes, int n_in,
                              void* d_out, int out_size, void* d_ws, size_t ws_size,
                              hipStream_t stream) {
    const float* x = (const float*)d_in[0];
    const int* ei = (const int*)d_in[1];
    const int* batch = (const int*)d_in[2];
    const float* Wl = (const float*)d_in[3];
    const float* bl = (const float*)d_in[4];
    const float* Wr = (const float*)d_in[5];
    const float* br = (const float*)d_in[6];
    const float* att = (const float*)d_in[7];
    const float* cb = (const float*)d_in[8];
    const float* lnw = (const float*)d_in[9];
    const float* lnb = (const float*)d_in[10];
    const float* linw = (const float*)d_in[11];
    const float* linb = (const float*)d_in[12];
    float* y = (float*)d_out;

    char* ws = (char*)d_ws;
    uint2* xlh = (uint2*)ws;                                     // N*16 uint2
    uint2* xrh = (uint2*)(ws + (size_t)N_NODES * 128);           // N*16 uint2
    float* gsum = (float*)(ws + (size_t)N_NODES * 256);          // 64*64
    float* gcnt = gsum + N_GRAPHS * HID;                         // 64
    double* stats = (double*)(gcnt + N_GRAPHS);                  // 2 doubles
    int* rowptr = (int*)(stats + 2);                             // N+1
    int* deg = rowptr + (N_NODES + 1);                           // N
    int* bsum = deg + N_NODES;                                   // 512 (391 used)
    int* erank = bsum + 512;                                     // E
    int* esrc = erank + N_EDGES;                                 // E

    k0_transform<<<(N_NODES * 16 + 255) / 256, 256, 0, stream>>>(
        x, Wl, bl, Wr, br, xlh, xrh, deg, gsum, gcnt, stats);
    ka_rank<<<(N_EDGES / 4 + 255) / 256, 256, 0, stream>>>(ei, deg, erank);
    kb1_scan<<<NB_SCAN, 256, 0, stream>>>(deg, rowptr, bsum);
    kb2_scan<<<1, 512, 0, stream>>>(bsum);
    kc_place<<<512, 256, 0, stream>>>(ei, rowptr, bsum, erank, esrc);
    kd_node_agg<<<KD_BLOCKS, 256, 0, stream>>>(
        rowptr, bsum, esrc, xlh, xrh, att, cb, batch, gsum, gcnt, stats);
    k4_head<<<N_GRAPHS, 64, 0, stream>>>(gsum, gcnt, stats, lnw, lnb, linw, linb, y);
}

// Round 14
// 350.349 us; speedup vs baseline: 1.3778x; 1.0620x over previous
//
#include <hip/hip_runtime.h>
#include <math.h>

#define N_NODES 100000
#define N_EDGES 1600000
#define N_GRAPHS 64
#define HID 64
#define LN_EPS 1e-5f
#define NB_SCAN ((N_NODES + 255) / 256)   // 391 scan blocks
#define K0_BLOCKS ((N_NODES * 16 + 255) / 256)   // 6250
#define KA_BLOCKS ((N_EDGES / 4 + 255) / 256)    // 1563
#define KD_BLOCKS 2048
#define KD_WAVES (KD_BLOCKS * 4)          // 8192 waves (proven: more waves only
                                          // add gsum-atomic contention, R13)
#define KD_CHUNK ((N_NODES + KD_WAVES - 1) / KD_WAVES)  // 13 contiguous nodes/wave

__device__ __forceinline__ float waveReduceSum(float v) {
#pragma unroll
    for (int off = 32; off > 0; off >>= 1)
        v += __shfl_xor(v, off, 64);
    return v;
}

__device__ __forceinline__ float groupReduceSum16(float v) {
#pragma unroll
    for (int off = 8; off > 0; off >>= 1)
        v += __shfl_xor(v, off, 64);
    return v;
}

__device__ __forceinline__ unsigned rne_bf16(float f) {
    unsigned u = __float_as_uint(f);
    return (u + 0x7fffu + ((u >> 16) & 1u)) >> 16;
}

// K0A: grid-union fusion of node transforms (blocks [0,K0_BLOCKS)) and the
// edge histogram/rank capture (blocks [K0_BLOCKS,..)). Independent work —
// deg is pre-zeroed by hipMemsetAsync — so the two phases overlap on the CU
// array (k0 is BW-bound, ka is atomic-latency-bound; union runs ~max not sum).
__global__ __launch_bounds__(256) void k0a_fused(
    const float* __restrict__ x,
    const float* __restrict__ Wl, const float* __restrict__ bl,
    const float* __restrict__ Wr, const float* __restrict__ br,
    uint2* __restrict__ xlh, uint2* __restrict__ xrh,
    const int* __restrict__ ei,
    int* __restrict__ deg, int* __restrict__ erank,
    float* __restrict__ gsum, float* __restrict__ gcnt,
    double* __restrict__ stats) {
    if (blockIdx.x < K0_BLOCKS) {
        // ---- node-transform part (old k0) ----
        if (blockIdx.x == 0) {
            for (int i = threadIdx.x; i < N_GRAPHS * HID; i += blockDim.x)
                gsum[i] = 0.f;
            if (threadIdx.x < N_GRAPHS) gcnt[threadIdx.x] = 0.f;
            if (threadIdx.x < 2) stats[threadIdx.x] = 0.0;
        }
        int t = blockIdx.x * blockDim.x + threadIdx.x;
        int n = t >> 4;
        int cg = t & 15;
        if (n >= N_NODES) return;
        float4 xv = ((const float4*)x)[n];
        float4 w0 = ((const float4*)Wl)[0 * 16 + cg];
        float4 w1 = ((const float4*)Wl)[1 * 16 + cg];
        float4 w2 = ((const float4*)Wl)[2 * 16 + cg];
        float4 w3 = ((const float4*)Wl)[3 * 16 + cg];
        float4 bv = ((const float4*)bl)[cg];
        float4 vl;
        vl.x = bv.x + xv.x * w0.x + xv.y * w1.x + xv.z * w2.x + xv.w * w3.x;
        vl.y = bv.y + xv.x * w0.y + xv.y * w1.y + xv.z * w2.y + xv.w * w3.y;
        vl.z = bv.z + xv.x * w0.z + xv.y * w1.z + xv.z * w2.z + xv.w * w3.z;
        vl.w = bv.w + xv.x * w0.w + xv.y * w1.w + xv.z * w2.w + xv.w * w3.w;
        w0 = ((const float4*)Wr)[0 * 16 + cg];
        w1 = ((const float4*)Wr)[1 * 16 + cg];
        w2 = ((const float4*)Wr)[2 * 16 + cg];
        w3 = ((const float4*)Wr)[3 * 16 + cg];
        bv = ((const float4*)br)[cg];
        float4 vr;
        vr.x = bv.x + xv.x * w0.x + xv.y * w1.x + xv.z * w2.x + xv.w * w3.x;
        vr.y = bv.y + xv.x * w0.y + xv.y * w1.y + xv.z * w2.y + xv.w * w3.y;
        vr.z = bv.z + xv.x * w0.z + xv.y * w1.z + xv.z * w2.z + xv.w * w3.z;
        vr.w = bv.w + xv.x * w0.w + xv.y * w1.w + xv.z * w2.w + xv.w * w3.w;
        uint2 p;
        p.x = rne_bf16(vl.x) | (rne_bf16(vl.y) << 16);
        p.y = rne_bf16(vl.z) | (rne_bf16(vl.w) << 16);
        xlh[n * 16 + cg] = p;
        uint2 r;
        r.x = rne_bf16(vr.x) | (rne_bf16(vr.y) << 16);
        r.y = rne_bf16(vr.z) | (rne_bf16(vr.w) << 16);
        xrh[n * 16 + cg] = r;
    } else {
        // ---- edge histogram + rank part (old ka) ----
        int q = (blockIdx.x - K0_BLOCKS) * blockDim.x + threadIdx.x;
        if (q >= N_EDGES / 4) return;
        int4 d4 = ((const int4*)(ei + N_EDGES))[q];
        int4 r4;
        r4.x = atomicAdd(&deg[d4.x], 1);
        r4.y = atomicAdd(&deg[d4.y], 1);
        r4.z = atomicAdd(&deg[d4.z], 1);
        r4.w = atomicAdd(&deg[d4.w], 1);
        ((int4*)erank)[q] = r4;
    }
}

// KB1: per-block exclusive scan of deg -> rowptr (block-local) + block totals.
__global__ __launch_bounds__(256) void kb1_scan(const int* __restrict__ deg,
                                                int* __restrict__ rowptr,
                                                int* __restrict__ bsum) {
    __shared__ int s[256];
    int i = blockIdx.x * 256 + threadIdx.x;
    int v = (i < N_NODES) ? deg[i] : 0;
    s[threadIdx.x] = v;
    __syncthreads();
#pragma unroll
    for (int off = 1; off < 256; off <<= 1) {
        int t = (threadIdx.x >= off) ? s[threadIdx.x - off] : 0;
        __syncthreads();
        s[threadIdx.x] += t;
        __syncthreads();
    }
    if (i < N_NODES) rowptr[i] = s[threadIdx.x] - v;  // block-local exclusive
    if (threadIdx.x == 255) bsum[blockIdx.x] = s[255];
}

// KB2: single-block exclusive scan of block totals (NB_SCAN=391 <= 512).
// Consumers (kc, kd) add bsum[x>>8] on the fly.
__global__ __launch_bounds__(512) void kb2_scan(int* __restrict__ bsum) {
    __shared__ int s[512];
    int v = (threadIdx.x < NB_SCAN) ? bsum[threadIdx.x] : 0;
    s[threadIdx.x] = v;
    __syncthreads();
#pragma unroll
    for (int off = 1; off < 512; off <<= 1) {
        int t = (threadIdx.x >= off) ? s[threadIdx.x - off] : 0;
        __syncthreads();
        s[threadIdx.x] += t;
        __syncthreads();
    }
    if (threadIdx.x < NB_SCAN) bsum[threadIdx.x] = s[threadIdx.x] - v;
}

// KC: atomic-free rank-based placement, XCD-partitioned by dst (write-merge).
__global__ __launch_bounds__(256) void kc_place(const int* __restrict__ ei,
                                                const int* __restrict__ rowptr,
                                                const int* __restrict__ bsum,
                                                const int* __restrict__ erank,
                                                int* __restrict__ esrc) {
    int xcd = blockIdx.x & 7;
    int sub = blockIdx.x >> 3;                 // 0..63
    int lo = xcd * (N_NODES / 8);
    int hi = lo + (N_NODES / 8);
    int tid = sub * 256 + (int)threadIdx.x;
    for (int q = tid; q < N_EDGES / 4; q += 64 * 256) {
        int4 d4 = ((const int4*)(ei + N_EDGES))[q];
        int i0 = q * 4;
        if (d4.x >= lo && d4.x < hi)
            esrc[rowptr[d4.x] + bsum[d4.x >> 8] + erank[i0 + 0]] = ei[i0 + 0];
        if (d4.y >= lo && d4.y < hi)
            esrc[rowptr[d4.y] + bsum[d4.y >> 8] + erank[i0 + 1]] = ei[i0 + 1];
        if (d4.z >= lo && d4.z < hi)
            esrc[rowptr[d4.z] + bsum[d4.z >> 8] + erank[i0 + 2]] = ei[i0 + 2];
        if (d4.w >= lo && d4.w < hi)
            esrc[rowptr[d4.w] + bsum[d4.w >> 8] + erank[i0 + 3]] = ei[i0 + 3];
    }
}

// KD: fused node aggregation + LN stats + graph pooling. SETTLED config:
// proven 4-slot x 16-lane uint2 body, bf16 xr, 2048 blocks / chunk 13.
// (R7/R9: wider ILP spills; R12: fence fusion stalls; R13: more waves just
// add gsum-atomic contention. Do not touch.)
__global__ __launch_bounds__(256, 8) void kd_node_agg(
    const int* __restrict__ rowptr, const int* __restrict__ bsum,
    const int* __restrict__ esrc,
    const uint2* __restrict__ xlh, const uint2* __restrict__ xrh,
    const float* __restrict__ att, const float* __restrict__ cb,
    const int* __restrict__ batch,
    float* __restrict__ gsum, float* __restrict__ gcnt,
    double* __restrict__ stats) {
    __shared__ float sS[4], sQ[4];
    int w = threadIdx.x >> 6;             // wave-in-block 0..3
    int lane = threadIdx.x & 63;
    int slot = lane >> 4;                 // 0..3: edge slot
    int cg = lane & 15;                   // channel group (4 ch)
    int wid = blockIdx.x * 4 + w;
    int n0 = wid * KD_CHUNK;
    int n1 = min(n0 + KD_CHUNK, N_NODES);

    float4 av = ((const float4*)att)[cg];
    float4 cv = ((const float4*)cb)[cg];

    float lsum = 0.f, lsq = 0.f;
    float gacc0 = 0.f, gacc1 = 0.f, gacc2 = 0.f, gacc3 = 0.f;
    float runcnt = 0.f;
    int cur_g = -1;

    for (int n = n0; n < n1; ++n) {
        int beg = rowptr[n] + bsum[n >> 8];
        int end = (n + 1 < N_NODES) ? (rowptr[n + 1] + bsum[(n + 1) >> 8]) : N_EDGES;
        uint2 rp = xrh[n * 16 + cg];
        float4 xr;
        xr.x = __uint_as_float(rp.x << 16);
        xr.y = __uint_as_float(rp.x & 0xffff0000u);
        xr.z = __uint_as_float(rp.y << 16);
        xr.w = __uint_as_float(rp.y & 0xffff0000u);
        float num0 = 0.f, num1 = 0.f, num2 = 0.f, num3 = 0.f, den = 0.f;
        int j = beg + slot;
        uint2 p = make_uint2(0, 0);
        if (j < end) p = xlh[esrc[j] * 16 + cg];
        for (int j0 = beg; j0 < end; j0 += 4) {
            uint2 pc = p;
            bool vc = (j0 + slot) < end;
            int jn = j0 + 4 + slot;
            if (jn < end) p = xlh[esrc[jn] * 16 + cg];
            float f0 = __uint_as_float(pc.x << 16);
            float f1 = __uint_as_float(pc.x & 0xffff0000u);
            float f2 = __uint_as_float(pc.y << 16);
            float f3 = __uint_as_float(pc.y & 0xffff0000u);
            float h0 = f0 + xr.x, h1 = f1 + xr.y, h2 = f2 + xr.z, h3 = f3 + xr.w;
            float l0 = fmaxf(h0, 0.f) + 0.2f * fminf(h0, 0.f);
            float l1 = fmaxf(h1, 0.f) + 0.2f * fminf(h1, 0.f);
            float l2 = fmaxf(h2, 0.f) + 0.2f * fminf(h2, 0.f);
            float l3 = fmaxf(h3, 0.f) + 0.2f * fminf(h3, 0.f);
            float part = l0 * av.x + l1 * av.y + l2 * av.z + l3 * av.w;
            float e = groupReduceSum16(part);   // within-slot 16-lane reduce
            float ex = vc ? __expf(e) : 0.f;
            den += ex;
            num0 += ex * f0; num1 += ex * f1; num2 += ex * f2; num3 += ex * f3;
        }
#pragma unroll
        for (int off = 16; off <= 32; off <<= 1) {
            num0 += __shfl_xor(num0, off, 64);
            num1 += __shfl_xor(num1, off, 64);
            num2 += __shfl_xor(num2, off, 64);
            num3 += __shfl_xor(num3, off, 64);
            den += __shfl_xor(den, off, 64);
        }
        float inv = (den > 0.f) ? (1.f / den) : 0.f;
        float v0 = fmaxf(num0 * inv + cv.x, 0.f);
        float v1 = fmaxf(num1 * inv + cv.y, 0.f);
        float v2 = fmaxf(num2 * inv + cv.z, 0.f);
        float v3 = fmaxf(num3 * inv + cv.w, 0.f);
        if (slot == 0) {   // values replicated across slots; count once
            lsum += v0 + v1 + v2 + v3;
            lsq += v0 * v0 + v1 * v1 + v2 * v2 + v3 * v3;
            int g = batch[n];
            if (g != cur_g) {
                if (cur_g >= 0) {
                    unsafeAtomicAdd(&gsum[cur_g * HID + cg * 4 + 0], gacc0);
                    unsafeAtomicAdd(&gsum[cur_g * HID + cg * 4 + 1], gacc1);
                    unsafeAtomicAdd(&gsum[cur_g * HID + cg * 4 + 2], gacc2);
                    unsafeAtomicAdd(&gsum[cur_g * HID + cg * 4 + 3], gacc3);
                    if (cg == 0) unsafeAtomicAdd(&gcnt[cur_g], runcnt);
                }
                cur_g = g;
                gacc0 = gacc1 = gacc2 = gacc3 = 0.f;
                runcnt = 0.f;
            }
            gacc0 += v0; gacc1 += v1; gacc2 += v2; gacc3 += v3;
            runcnt += 1.f;
        }
    }
    if (cur_g >= 0) {   // only slot-0 lanes have cur_g >= 0
        unsafeAtomicAdd(&gsum[cur_g * HID + cg * 4 + 0], gacc0);
        unsafeAtomicAdd(&gsum[cur_g * HID + cg * 4 + 1], gacc1);
        unsafeAtomicAdd(&gsum[cur_g * HID + cg * 4 + 2], gacc2);
        unsafeAtomicAdd(&gsum[cur_g * HID + cg * 4 + 3], gacc3);
        if (cg == 0) unsafeAtomicAdd(&gcnt[cur_g], runcnt);
    }
    lsum = groupReduceSum16(lsum);
    lsq = groupReduceSum16(lsq);
    if (lane == 0) { sS[w] = lsum; sQ[w] = lsq; }
    __syncthreads();
    if (threadIdx.x == 0) {
        double ds = 0.0, dq = 0.0;
#pragma unroll
        for (int i = 0; i < 4; ++i) { ds += (double)sS[i]; dq += (double)sQ[i]; }
        unsafeAtomicAdd(&stats[0], ds);
        unsafeAtomicAdd(&stats[1], dq);
    }
}

// K4: per-graph head (separate launch; fence fusion cost 135us — R12).
__global__ __launch_bounds__(64) void k4_head(
    const float* __restrict__ gsum, const float* __restrict__ gcnt,
    const double* __restrict__ stats,
    const float* __restrict__ lnw, const float* __restrict__ lnb,
    const float* __restrict__ linw, const float* __restrict__ linb,
    float* __restrict__ y) {
    int g = blockIdx.x;
    int lane = threadIdx.x;
    double tot = (double)N_NODES * (double)HID;
    double mu = stats[0] / tot;
    double var = stats[1] / tot - mu * mu;
    float rs = rsqrtf((float)var + LN_EPS);
    float cnt = fmaxf(gcnt[g], 1.f);
    float pooled = (gsum[g * HID + lane] / cnt - (float)mu) * rs * lnw[lane] + lnb[lane];
    float t = waveReduceSum(pooled * linw[lane]);
    if (lane == 0) {
        float z = t + linb[0];
        y[g] = 1.f / (1.f + __expf(-z));
    }
}

extern "C" void kernel_launch(void* const* d_in, const int* in_sizes, int n_in,
                              void* d_out, int out_size, void* d_ws, size_t ws_size,
                              hipStream_t stream) {
    const float* x = (const float*)d_in[0];
    const int* ei = (const int*)d_in[1];
    const int* batch = (const int*)d_in[2];
    const float* Wl = (const float*)d_in[3];
    const float* bl = (const float*)d_in[4];
    const float* Wr = (const float*)d_in[5];
    const float* br = (const float*)d_in[6];
    const float* att = (const float*)d_in[7];
    const float* cb = (const float*)d_in[8];
    const float* lnw = (const float*)d_in[9];
    const float* lnb = (const float*)d_in[10];
    const float* linw = (const float*)d_in[11];
    const float* linb = (const float*)d_in[12];
    float* y = (float*)d_out;

    char* ws = (char*)d_ws;
    uint2* xlh = (uint2*)ws;                                     // N*16 uint2
    uint2* xrh = (uint2*)(ws + (size_t)N_NODES * 128);           // N*16 uint2
    float* gsum = (float*)(ws + (size_t)N_NODES * 256);          // 64*64
    float* gcnt = gsum + N_GRAPHS * HID;                         // 64
    double* stats = (double*)(gcnt + N_GRAPHS);                  // 2 doubles
    int* rowptr = (int*)(stats + 2);                             // N+1
    int* deg = rowptr + (N_NODES + 1);                           // N
    int* bsum = deg + N_NODES;                                   // 512 (391 used)
    int* erank = bsum + 512;                                     // E
    int* esrc = erank + N_EDGES;                                 // E

    hipMemsetAsync(deg, 0, N_NODES * sizeof(int), stream);
    k0a_fused<<<K0_BLOCKS + KA_BLOCKS, 256, 0, stream>>>(
        x, Wl, bl, Wr, br, xlh, xrh, ei, deg, erank, gsum, gcnt, stats);
    kb1_scan<<<NB_SCAN, 256, 0, stream>>>(deg, rowptr, bsum);
    kb2_scan<<<1, 512, 0, stream>>>(bsum);
    kc_place<<<512, 256, 0, stream>>>(ei, rowptr, bsum, erank, esrc);
    kd_node_agg<<<KD_BLOCKS, 256, 0, stream>>>(
        rowptr, bsum, esrc, xlh, xrh, att, cb, batch, gsum, gcnt, stats);
    k4_head<<<N_GRAPHS, 64, 0, stream>>>(gsum, gcnt, stats, lnw, lnb, linw, linb, y);
}

// Round 15
// 277.874 us; speedup vs baseline: 1.7371x; 1.2608x over previous
//
#include <hip/hip_runtime.h>
#include <math.h>

#define N_NODES 100000
#define N_EDGES 1600000
#define N_GRAPHS 64
#define HID 64
#define LN_EPS 1e-5f
#define ECAP 32                           // per-node edge-slot capacity
#define KD_BLOCKS 2048
#define KD_WAVES (KD_BLOCKS * 4)          // 8192 waves (settled, R13)
#define KD_CHUNK ((N_NODES + KD_WAVES - 1) / KD_WAVES)  // 13 contiguous nodes/wave

__device__ __forceinline__ float waveReduceSum(float v) {
#pragma unroll
    for (int off = 32; off > 0; off >>= 1)
        v += __shfl_xor(v, off, 64);
    return v;
}

__device__ __forceinline__ float groupReduceSum16(float v) {
#pragma unroll
    for (int off = 8; off > 0; off >>= 1)
        v += __shfl_xor(v, off, 64);
    return v;
}

__device__ __forceinline__ unsigned rne_bf16(float f) {
    unsigned u = __float_as_uint(f);
    return (u + 0x7fffu + ((u >> 16) & 1u)) >> 16;
}

// K0: per-node transforms (xl, xr packed bf16) + all workspace init.
__global__ __launch_bounds__(256) void k0_transform(
    const float* __restrict__ x,
    const float* __restrict__ Wl, const float* __restrict__ bl,
    const float* __restrict__ Wr, const float* __restrict__ br,
    uint2* __restrict__ xlh, uint2* __restrict__ xrh,
    int* __restrict__ deg, int* __restrict__ ovf_cnt,
    float* __restrict__ gsum, float* __restrict__ gcnt,
    double* __restrict__ stats) {
    if (blockIdx.x == 0) {
        for (int i = threadIdx.x; i < N_GRAPHS * HID; i += blockDim.x) gsum[i] = 0.f;
        if (threadIdx.x < N_GRAPHS) gcnt[threadIdx.x] = 0.f;
        if (threadIdx.x < 2) stats[threadIdx.x] = 0.0;
        if (threadIdx.x == 0) *ovf_cnt = 0;
    }
    int t = blockIdx.x * blockDim.x + threadIdx.x;
    int n = t >> 4;
    int cg = t & 15;
    if (n >= N_NODES) return;
    float4 xv = ((const float4*)x)[n];
    float4 w0 = ((const float4*)Wl)[0 * 16 + cg];
    float4 w1 = ((const float4*)Wl)[1 * 16 + cg];
    float4 w2 = ((const float4*)Wl)[2 * 16 + cg];
    float4 w3 = ((const float4*)Wl)[3 * 16 + cg];
    float4 bv = ((const float4*)bl)[cg];
    float4 vl;
    vl.x = bv.x + xv.x * w0.x + xv.y * w1.x + xv.z * w2.x + xv.w * w3.x;
    vl.y = bv.y + xv.x * w0.y + xv.y * w1.y + xv.z * w2.y + xv.w * w3.y;
    vl.z = bv.z + xv.x * w0.z + xv.y * w1.z + xv.z * w2.z + xv.w * w3.z;
    vl.w = bv.w + xv.x * w0.w + xv.y * w1.w + xv.z * w2.w + xv.w * w3.w;
    w0 = ((const float4*)Wr)[0 * 16 + cg];
    w1 = ((const float4*)Wr)[1 * 16 + cg];
    w2 = ((const float4*)Wr)[2 * 16 + cg];
    w3 = ((const float4*)Wr)[3 * 16 + cg];
    bv = ((const float4*)br)[cg];
    float4 vr;
    vr.x = bv.x + xv.x * w0.x + xv.y * w1.x + xv.z * w2.x + xv.w * w3.x;
    vr.y = bv.y + xv.x * w0.y + xv.y * w1.y + xv.z * w2.y + xv.w * w3.y;
    vr.z = bv.z + xv.x * w0.z + xv.y * w1.z + xv.z * w2.z + xv.w * w3.z;
    vr.w = bv.w + xv.x * w0.w + xv.y * w1.w + xv.z * w2.w + xv.w * w3.w;
    uint2 p;
    p.x = rne_bf16(vl.x) | (rne_bf16(vl.y) << 16);
    p.y = rne_bf16(vl.z) | (rne_bf16(vl.w) << 16);
    xlh[n * 16 + cg] = p;
    uint2 r;
    r.x = rne_bf16(vr.x) | (rne_bf16(vr.y) << 16);
    r.y = rne_bf16(vr.z) | (rne_bf16(vr.w) << 16);
    xrh[n * 16 + cg] = r;
    if (cg == 0) deg[n] = 0;
}

// KA: direct-placement histogram — replaces the whole rowptr-scan + place
// pipeline (kb1/kb2/kc deleted). rank = atomicAdd(deg); rank<ECAP edges go
// straight to esrc[dst*ECAP+rank]; rare overflow (P(deg>32)~3e-5, ~3 nodes)
// appends (dst,src) to an overflow list handled correctly by kd.
// XCD-partitioned by dst (R6-proven): esrc slice = 1.6MB/XCD -> writes merge
// in the owning L2 instead of 1.6M full-line HBM writebacks.
__global__ __launch_bounds__(256) void ka_direct(const int* __restrict__ ei,
                                                 int* __restrict__ deg,
                                                 int* __restrict__ esrc,
                                                 int2* __restrict__ ovf,
                                                 int* __restrict__ ovf_cnt) {
    int xcd = blockIdx.x & 7;
    int sub = blockIdx.x >> 3;                 // 0..63
    int lo = xcd * (N_NODES / 8);
    int hi = lo + (N_NODES / 8);
    int tid = sub * 256 + (int)threadIdx.x;
    for (int q = tid; q < N_EDGES / 4; q += 64 * 256) {
        int4 d4 = ((const int4*)(ei + N_EDGES))[q];
        int4 s4 = ((const int4*)ei)[q];
#pragma unroll
        for (int k = 0; k < 4; ++k) {
            int d = (k == 0) ? d4.x : (k == 1) ? d4.y : (k == 2) ? d4.z : d4.w;
            int s = (k == 0) ? s4.x : (k == 1) ? s4.y : (k == 2) ? s4.z : s4.w;
            if (d >= lo && d < hi) {
                int r = atomicAdd(&deg[d], 1);
                if (r < ECAP) {
                    esrc[d * ECAP + r] = s;
                } else {
                    int o = atomicAdd(ovf_cnt, 1);
                    ovf[o] = make_int2(d, s);
                }
            }
        }
    }
}

// KD: fused node aggregation + LN stats + graph pooling. SETTLED body
// (4 slots x 16 lanes, uint2, VGPR 32, 2048 blocks — R7/R9/R12/R13 lessons).
// Indexing simplified to padded layout: base = n*ECAP, count = deg[n];
// deg>ECAP falls back to scanning the (tiny) overflow list.
__global__ __launch_bounds__(256, 8) void kd_node_agg(
    const int* __restrict__ deg, const int* __restrict__ esrc,
    const int2* __restrict__ ovf, const int* __restrict__ ovf_cnt,
    const uint2* __restrict__ xlh, const uint2* __restrict__ xrh,
    const float* __restrict__ att, const float* __restrict__ cb,
    const int* __restrict__ batch,
    float* __restrict__ gsum, float* __restrict__ gcnt,
    double* __restrict__ stats) {
    __shared__ float sS[4], sQ[4];
    int w = threadIdx.x >> 6;             // wave-in-block 0..3
    int lane = threadIdx.x & 63;
    int slot = lane >> 4;                 // 0..3: edge slot
    int cg = lane & 15;                   // channel group (4 ch)
    int wid = blockIdx.x * 4 + w;
    int n0 = wid * KD_CHUNK;
    int n1 = min(n0 + KD_CHUNK, N_NODES);

    float4 av = ((const float4*)att)[cg];
    float4 cv = ((const float4*)cb)[cg];

    float lsum = 0.f, lsq = 0.f;
    float gacc0 = 0.f, gacc1 = 0.f, gacc2 = 0.f, gacc3 = 0.f;
    float runcnt = 0.f;
    int cur_g = -1;

    for (int n = n0; n < n1; ++n) {
        int dtot = deg[n];
        int dpk = min(dtot, ECAP);
        int base = n * ECAP;
        uint2 rp = xrh[n * 16 + cg];
        float4 xr;
        xr.x = __uint_as_float(rp.x << 16);
        xr.y = __uint_as_float(rp.x & 0xffff0000u);
        xr.z = __uint_as_float(rp.y << 16);
        xr.w = __uint_as_float(rp.y & 0xffff0000u);
        float num0 = 0.f, num1 = 0.f, num2 = 0.f, num3 = 0.f, den = 0.f;
        int j = slot;
        uint2 p = make_uint2(0, 0);
        if (j < dpk) p = xlh[esrc[base + j] * 16 + cg];
        for (int j0 = 0; j0 < dpk; j0 += 4) {
            uint2 pc = p;
            bool vc = (j0 + slot) < dpk;
            int jn = j0 + 4 + slot;
            if (jn < dpk) p = xlh[esrc[base + jn] * 16 + cg];
            float f0 = __uint_as_float(pc.x << 16);
            float f1 = __uint_as_float(pc.x & 0xffff0000u);
            float f2 = __uint_as_float(pc.y << 16);
            float f3 = __uint_as_float(pc.y & 0xffff0000u);
            float h0 = f0 + xr.x, h1 = f1 + xr.y, h2 = f2 + xr.z, h3 = f3 + xr.w;
            float l0 = fmaxf(h0, 0.f) + 0.2f * fminf(h0, 0.f);
            float l1 = fmaxf(h1, 0.f) + 0.2f * fminf(h1, 0.f);
            float l2 = fmaxf(h2, 0.f) + 0.2f * fminf(h2, 0.f);
            float l3 = fmaxf(h3, 0.f) + 0.2f * fminf(h3, 0.f);
            float part = l0 * av.x + l1 * av.y + l2 * av.z + l3 * av.w;
            float e = groupReduceSum16(part);   // within-slot 16-lane reduce
            float ex = vc ? __expf(e) : 0.f;
            den += ex;
            num0 += ex * f0; num1 += ex * f1; num2 += ex * f2; num3 += ex * f3;
        }
        if (dtot > ECAP) {   // overflow fallback: scan tiny (dst,src) list
            int m = *ovf_cnt;
            for (int t = 0; t < m; ++t) {
                int2 od = ovf[t];
                if (od.x != n) continue;
                uint2 pc = make_uint2(0, 0);
                if (slot == 0) pc = xlh[od.y * 16 + cg];
                float f0 = __uint_as_float(pc.x << 16);
                float f1 = __uint_as_float(pc.x & 0xffff0000u);
                float f2 = __uint_as_float(pc.y << 16);
                float f3 = __uint_as_float(pc.y & 0xffff0000u);
                float h0 = f0 + xr.x, h1 = f1 + xr.y, h2 = f2 + xr.z, h3 = f3 + xr.w;
                float l0 = fmaxf(h0, 0.f) + 0.2f * fminf(h0, 0.f);
                float l1 = fmaxf(h1, 0.f) + 0.2f * fminf(h1, 0.f);
                float l2 = fmaxf(h2, 0.f) + 0.2f * fminf(h2, 0.f);
                float l3 = fmaxf(h3, 0.f) + 0.2f * fminf(h3, 0.f);
                float part = l0 * av.x + l1 * av.y + l2 * av.z + l3 * av.w;
                float e = groupReduceSum16(part);
                float ex = (slot == 0) ? __expf(e) : 0.f;
                den += ex;
                num0 += ex * f0; num1 += ex * f1; num2 += ex * f2; num3 += ex * f3;
            }
        }
#pragma unroll
        for (int off = 16; off <= 32; off <<= 1) {
            num0 += __shfl_xor(num0, off, 64);
            num1 += __shfl_xor(num1, off, 64);
            num2 += __shfl_xor(num2, off, 64);
            num3 += __shfl_xor(num3, off, 64);
            den += __shfl_xor(den, off, 64);
        }
        float inv = (den > 0.f) ? (1.f / den) : 0.f;
        float v0 = fmaxf(num0 * inv + cv.x, 0.f);
        float v1 = fmaxf(num1 * inv + cv.y, 0.f);
        float v2 = fmaxf(num2 * inv + cv.z, 0.f);
        float v3 = fmaxf(num3 * inv + cv.w, 0.f);
        if (slot == 0) {   // values replicated across slots; count once
            lsum += v0 + v1 + v2 + v3;
            lsq += v0 * v0 + v1 * v1 + v2 * v2 + v3 * v3;
            int g = batch[n];
            if (g != cur_g) {
                if (cur_g >= 0) {
                    unsafeAtomicAdd(&gsum[cur_g * HID + cg * 4 + 0], gacc0);
                    unsafeAtomicAdd(&gsum[cur_g * HID + cg * 4 + 1], gacc1);
                    unsafeAtomicAdd(&gsum[cur_g * HID + cg * 4 + 2], gacc2);
                    unsafeAtomicAdd(&gsum[cur_g * HID + cg * 4 + 3], gacc3);
                    if (cg == 0) unsafeAtomicAdd(&gcnt[cur_g], runcnt);
                }
                cur_g = g;
                gacc0 = gacc1 = gacc2 = gacc3 = 0.f;
                runcnt = 0.f;
            }
            gacc0 += v0; gacc1 += v1; gacc2 += v2; gacc3 += v3;
            runcnt += 1.f;
        }
    }
    if (cur_g >= 0) {   // only slot-0 lanes have cur_g >= 0
        unsafeAtomicAdd(&gsum[cur_g * HID + cg * 4 + 0], gacc0);
        unsafeAtomicAdd(&gsum[cur_g * HID + cg * 4 + 1], gacc1);
        unsafeAtomicAdd(&gsum[cur_g * HID + cg * 4 + 2], gacc2);
        unsafeAtomicAdd(&gsum[cur_g * HID + cg * 4 + 3], gacc3);
        if (cg == 0) unsafeAtomicAdd(&gcnt[cur_g], runcnt);
    }
    lsum = groupReduceSum16(lsum);
    lsq = groupReduceSum16(lsq);
    if (lane == 0) { sS[w] = lsum; sQ[w] = lsq; }
    __syncthreads();
    if (threadIdx.x == 0) {
        double ds = 0.0, dq = 0.0;
#pragma unroll
        for (int i = 0; i < 4; ++i) { ds += (double)sS[i]; dq += (double)sQ[i]; }
        unsafeAtomicAdd(&stats[0], ds);
        unsafeAtomicAdd(&stats[1], dq);
    }
}

// K4: per-graph head (separate launch; fence fusion costs 135us — R12).
__global__ __launch_bounds__(64) void k4_head(
    const float* __restrict__ gsum, const float* __restrict__ gcnt,
    const double* __restrict__ stats,
    const float* __restrict__ lnw, const float* __restrict__ lnb,
    const float* __restrict__ linw, const float* __restrict__ linb,
    float* __restrict__ y) {
    int g = blockIdx.x;
    int lane = threadIdx.x;
    double tot = (double)N_NODES * (double)HID;
    double mu = stats[0] / tot;
    double var = stats[1] / tot - mu * mu;
    float rs = rsqrtf((float)var + LN_EPS);
    float cnt = fmaxf(gcnt[g], 1.f);
    float pooled = (gsum[g * HID + lane] / cnt - (float)mu) * rs * lnw[lane] + lnb[lane];
    float t = waveReduceSum(pooled * linw[lane]);
    if (lane == 0) {
        float z = t + linb[0];
        y[g] = 1.f / (1.f + __expf(-z));
    }
}

extern "C" void kernel_launch(void* const* d_in, const int* in_sizes, int n_in,
                              void* d_out, int out_size, void* d_ws, size_t ws_size,
                              hipStream_t stream) {
    const float* x = (const float*)d_in[0];
    const int* ei = (const int*)d_in[1];
    const int* batch = (const int*)d_in[2];
    const float* Wl = (const float*)d_in[3];
    const float* bl = (const float*)d_in[4];
    const float* Wr = (const float*)d_in[5];
    const float* br = (const float*)d_in[6];
    const float* att = (const float*)d_in[7];
    const float* cb = (const float*)d_in[8];
    const float* lnw = (const float*)d_in[9];
    const float* lnb = (const float*)d_in[10];
    const float* linw = (const float*)d_in[11];
    const float* linb = (const float*)d_in[12];
    float* y = (float*)d_out;

    char* ws = (char*)d_ws;
    uint2* xlh = (uint2*)ws;                                     // N*16 uint2 (12.8MB)
    uint2* xrh = (uint2*)(ws + (size_t)N_NODES * 128);           // N*16 uint2 (12.8MB)
    float* gsum = (float*)(ws + (size_t)N_NODES * 256);          // 64*64
    float* gcnt = gsum + N_GRAPHS * HID;                         // 64
    double* stats = (double*)(gcnt + N_GRAPHS);                  // 2 doubles
    int* deg = (int*)(stats + 2);                                // N
    int* ovf_cnt = deg + N_NODES;                                // 1 (+1 pad)
    int2* ovf = (int2*)(ovf_cnt + 2);                            // E int2 (12.8MB)
    int* esrc = (int*)(ovf + N_EDGES);                           // N*ECAP (12.8MB)

    k0_transform<<<(N_NODES * 16 + 255) / 256, 256, 0, stream>>>(
        x, Wl, bl, Wr, br, xlh, xrh, deg, ovf_cnt, gsum, gcnt, stats);
    ka_direct<<<512, 256, 0, stream>>>(ei, deg, esrc, ovf, ovf_cnt);
    kd_node_agg<<<KD_BLOCKS, 256, 0, stream>>>(
        deg, esrc, ovf, ovf_cnt, xlh, xrh, att, cb, batch, gsum, gcnt, stats);
    k4_head<<<N_GRAPHS, 64, 0, stream>>>(gsum, gcnt, stats, lnw, lnb, linw, linb, y);
}